// Round 7
// baseline (426.177 us; speedup 1.0000x reference)
//
#include <hip/hip_runtime.h>
#include <math.h>

// ---------------------------------------------------------------------------
// MLPAC_4_team fused v7: B=65536, P=3.
// v6 -> v7: fused kernel goes 512-thread / 8-wave blocks (same 64-sample
// tile): each wave owns a 32-col N-strip (acc[4][2]); 24 waves/CU at the
// same LDS (53248 B, 3 blocks/CU). Epilogues vectorized to f32x4 packed ops
// (v_pk_add/mul/max). Enc production: 3 groups x 6 kt, 1 kt/wave (waves 0-5).
// prep_kernel unchanged from v6. NOTE: ~80us bench-total gap above the fused
// dispatch is harness reset traffic (R6 falsified the "prep is slow" theory).
// ---------------------------------------------------------------------------

#define NEG_SLOPE 0.01f

// ws offsets in ushort elements
#define OFF_B1A  0
#define OFF_ENCB 9216
#define OFF_PW1  175104
#define OFF_PW2  617472
#define OFF_PW3  814080
#define WS_TOTAL 826368

// tile (512-short) boundaries
#define TILE_ENCB 18
#define TILE_PW1  342
#define TILE_PW2  1206
#define TILE_PW3  1590

#define OBS_STRIDE 48     // shorts/row (96 B)
#define HS_STRIDE  104    // shorts/row (96 used: ext0|ext1|opp)
#define ENC_STRIDE 200    // shorts/row (6*32 used)
#define H_STRIDE   264    // shorts/row (256 used)

typedef short bf16x8 __attribute__((ext_vector_type(8)));
typedef float f32x4  __attribute__((ext_vector_type(4)));
typedef float f32x2  __attribute__((ext_vector_type(2)));

__device__ __forceinline__ float lrelu(float x) { return fmaxf(x, NEG_SLOPE * x); }

__device__ __forceinline__ f32x4 lrelu4(f32x4 x) {
  return __builtin_elementwise_max(x, x * NEG_SLOPE);
}
__device__ __forceinline__ f32x4 splat4(float b) { return (f32x4){b, b, b, b}; }

__device__ __forceinline__ float u2f(unsigned int u) {
  union { unsigned int u; float f; } c; c.u = u; return c.f;
}

// pack two f32 -> two bf16 (round-half-up) in one v_perm_b32
__device__ __forceinline__ unsigned int pk2bf(float a, float b) {
  union { float f; unsigned int u; } ca, cb; ca.f = a; cb.f = b;
  return __builtin_amdgcn_perm(cb.u + 0x8000u, ca.u + 0x8000u, 0x07060302u);
}

__device__ __forceinline__ unsigned short f2bf(float x) {  // RNE, prep only
  union { float f; unsigned int u; } c; c.f = x;
  unsigned int u = (c.u + 0x7fffu + ((c.u >> 16) & 1u)) >> 16;
  return (unsigned short)u;
}

// ---------------------------------------------------------------------------
// prep (v6): one thread = one frag row (lane) = 8 shorts = one uint4 store.
// B-frag layout: lane l holds B[k_pos=(l>>4)*8+j][n=l&15], j=0..7.
// kperm = (k_pos&1)*16 + (k_pos>>1) absorbs the pair-pack column permutation.
// ---------------------------------------------------------------------------
__global__ __launch_bounds__(256) void prep_kernel(
    const float* __restrict__ propW2, const float* __restrict__ extW1,
    const float* __restrict__ extW2,  const float* __restrict__ oppW1,
    const float* __restrict__ oppW2,  const float* __restrict__ piW1,
    const float* __restrict__ piW2,   const float* __restrict__ piW3,
    unsigned short* __restrict__ ws16)
{
  const int u = blockIdx.x * 256 + threadIdx.x;   // frag-row index
  if (u >= (WS_TOTAL >> 3)) return;
  const int lane = u & 63;
  const int t = u >> 6;                            // 512-short tile index
  const int lm = lane & 15;
  const int kbase = (lane >> 4) << 3;              // k_pos = kbase + j

  unsigned short o8[8];

  if (t < TILE_ENCB) {
    int s = t;
    const int nt2 = s & 1; s >>= 1;
    const int go = s % 3; const int p = s / 3;
    const int n = go * 32 + nt2 * 16 + lm;
    #pragma unroll
    for (int j = 0; j < 8; ++j) {
      const int d = 16 + kbase + j;
      float v;
      if (n < 64) {
        const int g = n >> 5, o = n & 31, i = d - 18 - 6 * g;
        v = (i >= 0 && i < 6) ? extW1[((p * 2 + g) * 6 + i) * 32 + o] : 0.f;
      } else {
        const int o = n - 64, i = d - 30;
        v = (i >= 0) ? oppW1[(p * 18 + i) * 32 + o] : 0.f;
      }
      o8[j] = f2bf(v);
    }
  } else if (t < TILE_PW1) {
    int s = t - TILE_ENCB;
    const int nt2 = s & 1; s >>= 1;
    const int br = s % 3; s /= 3;
    const int kt = s % 18; const int p = s / 18;
    const int n = kt * 32 + nt2 * 16 + lm;
    #pragma unroll
    for (int j = 0; j < 8; ++j) {
      const int k_pos = kbase + j;
      const int kperm = (k_pos & 1) * 16 + (k_pos >> 1);
      float v;
      if (br == 0)      { const int g = kt >> 1;   v = propW2[((p*9+g)*32 + k_pos)*64 + (n - g*64)]; }
      else if (br == 1) { const int g = (kt >= 9); v = extW2 [((p*2+g)*32 + kperm)*288 + (n - g*288)]; }
      else              {                          v = oppW2 [(p*32 + kperm)*576 + n]; }
      o8[j] = f2bf(v);
    }
  } else if (t < TILE_PW2) {
    int s = t - TILE_PW1;
    const int nt = s & 15; s >>= 4;
    const int kt = s % 18; const int p = s / 18;
    const int col = nt * 16 + lm;
    #pragma unroll
    for (int j = 0; j < 8; ++j) {
      const int k_pos = kbase + j;
      const int kperm = (k_pos & 1) * 16 + (k_pos >> 1);
      o8[j] = f2bf(piW1[(p * 576 + kt * 32 + kperm) * 256 + col]);
    }
  } else if (t < TILE_PW3) {
    int s = t - TILE_PW2;
    const int nt = s & 15; s >>= 4;
    const int kt = s & 7; const int p = s >> 3;
    const int col = nt * 16 + lm;
    #pragma unroll
    for (int j = 0; j < 8; ++j) {
      const int k_pos = kbase + j;
      const int kperm = (k_pos & 1) * 16 + (k_pos >> 1);
      o8[j] = f2bf(piW2[(p * 256 + kt * 32 + kperm) * 256 + col]);
    }
  } else {
    int s = t - TILE_PW3;
    const int kt = s & 7; const int p = s >> 3;
    #pragma unroll
    for (int j = 0; j < 8; ++j) {
      const int k_pos = kbase + j;
      const int kperm = (k_pos & 1) * 16 + (k_pos >> 1);
      o8[j] = (lm < 3) ? f2bf(piW3[(p * 256 + kt * 32 + kperm) * 3 + lm]) : (unsigned short)0;
    }
  }

  *(uint4*)&ws16[(size_t)u * 8] = *(const uint4*)o8;
}

// ---------------------------------------------------------------------------
__global__ __launch_bounds__(512, 6) void fused_kernel(
    const float* __restrict__ obs,
    const float* __restrict__ propW1, const float* __restrict__ propB1,
    const float* __restrict__ propB2,
    const float* __restrict__ extB1,  const float* __restrict__ extB2,
    const float* __restrict__ oppB1,  const float* __restrict__ oppB2,
    const unsigned short* __restrict__ wsAll,
    const float* __restrict__ b1v, const float* __restrict__ b2v,
    const float* __restrict__ b3v,
    float* __restrict__ out)
{
  __shared__ __align__(16) unsigned short obs_s[64 * OBS_STRIDE]; //  6144 B
  __shared__ __align__(16) unsigned short Hs[64 * HS_STRIDE];     // 13312 B
  __shared__ __align__(16) unsigned short hbuf[64 * H_STRIDE];    // 33792 B
  // total 53248 B -> 3 blocks/CU (3*53248 = 159744 <= 163840), 24 waves/CU

  const unsigned short* b1aW = wsAll + OFF_B1A;
  const unsigned short* encB = wsAll + OFF_ENCB;
  const unsigned short* w1sw = wsAll + OFF_PW1;
  const unsigned short* w2sw = wsAll + OFF_PW2;
  const unsigned short* w3sw = wsAll + OFF_PW3;

  const int tid = threadIdx.x;
  const int p = blockIdx.y, brow = blockIdx.x;
  const int sbase = brow * 64;
  const int wv = tid >> 6, l = tid & 63, lm = l & 15, q = l >> 4;
  const f32x4 zz = {0.f, 0.f, 0.f, 0.f};

  // ---- phase 0: obs -> LDS bf16 (first 4 waves) ----
  if (tid < 256) {
    const int s = tid >> 2, c4 = tid & 3;
    if (c4 < 3) {
      const int c0 = c4 * 16;
      const float4* src = (const float4*)&obs[(sbase + s) * 144 + p * 48 + c0];
      float4 v0 = src[0], v1 = src[1], v2 = src[2], v3 = src[3];
      unsigned int pk[8];
      pk[0] = pk2bf(v0.x, v0.y); pk[1] = pk2bf(v0.z, v0.w);
      pk[2] = pk2bf(v1.x, v1.y); pk[3] = pk2bf(v1.z, v1.w);
      pk[4] = pk2bf(v2.x, v2.y); pk[5] = pk2bf(v2.z, v2.w);
      pk[6] = pk2bf(v3.x, v3.y); pk[7] = pk2bf(v3.z, v3.w);
      *(uint4*)&obs_s[s * OBS_STRIDE + c0]     = *(uint4*)&pk[0];
      *(uint4*)&obs_s[s * OBS_STRIDE + c0 + 8] = *(uint4*)&pk[4];
    }
  }
  __syncthreads();

  // ---- phase 1a: ext+opp layer-1 via MFMA (waves 1..3), bias in C ----
  if (wv >= 1 && wv <= 3) {
    const int go = wv - 1;                      // 0: ext0, 1: ext1, 2: opp
    bf16x8 af[4];
    #pragma unroll
    for (int ms = 0; ms < 4; ++ms)
      af[ms] = *(const bf16x8*)&obs_s[(ms * 16 + lm) * OBS_STRIDE + 16 + q * 8];
    bf16x8 bf0 = *(const bf16x8*)&b1aW[((p * 3 + go) * 2 + 0) * 512 + l * 8];
    bf16x8 bf1 = *(const bf16x8*)&b1aW[((p * 3 + go) * 2 + 1) * 512 + l * 8];
    float bias0, bias1;
    if (go < 2) { bias0 = extB1[(p*2+go)*32 + lm]; bias1 = extB1[(p*2+go)*32 + 16 + lm]; }
    else        { bias0 = oppB1[p*32 + lm];        bias1 = oppB1[p*32 + 16 + lm]; }
    const f32x4 cb0 = splat4(bias0), cb1 = splat4(bias1);
    #pragma unroll
    for (int ms = 0; ms < 4; ++ms) {
      f32x4 c0 = lrelu4(__builtin_amdgcn_mfma_f32_16x16x32_bf16(af[ms], bf0, cb0, 0, 0, 0));
      f32x4 c1 = lrelu4(__builtin_amdgcn_mfma_f32_16x16x32_bf16(af[ms], bf1, cb1, 0, 0, 0));
      #pragma unroll
      for (int r = 0; r < 4; ++r)
        *(unsigned int*)&Hs[(ms * 16 + q * 4 + r) * HS_STRIDE + go * 32 + lm * 2] =
            pk2bf(c0[r], c1[r]);
    }
  }
  __syncthreads();

  // ---- pi L1 bias preload + acc init (wave owns 32-col strip wv*32..) ----
  float b1r[2];
  #pragma unroll
  for (int nt = 0; nt < 2; ++nt) b1r[nt] = b1v[p * 256 + wv * 32 + nt * 16 + lm];
  f32x4 acc[4][2];
  #pragma unroll
  for (int a = 0; a < 4; ++a) {
    acc[a][0] = splat4(b1r[0]);
    acc[a][1] = splat4(b1r[1]);
  }

  // ---- enc: 3 groups x 6 kt (1 kt per wave, waves 0..5) + pi-L1 partial ----
  for (int g = 0; g < 3; ++g) {
    if (wv < 6) {
      const int kt = g * 6 + wv, ktloc = wv;
      const int gp = kt >> 1, ge = (kt >= 9) ? 1 : 0;

      // 1) prop-H A-frags first (prop weights die before W2 frags)
      bf16x8 apf[4];
      {
        f32x2 w0v[4], w1v[4], bbv[4];
        const float4* p4 = (const float4*)&propW1[(p * 9 + gp) * 64];
        float4 t0a = p4[q * 2],     t0b = p4[q * 2 + 1];
        float4 t1a = p4[8 + q * 2], t1b = p4[8 + q * 2 + 1];
        const float4* pb4 = (const float4*)&propB1[(p * 9 + gp) * 32];
        float4 tba = pb4[q * 2],    tbb = pb4[q * 2 + 1];
        w0v[0] = (f32x2){t0a.x, t0a.y}; w0v[1] = (f32x2){t0a.z, t0a.w};
        w0v[2] = (f32x2){t0b.x, t0b.y}; w0v[3] = (f32x2){t0b.z, t0b.w};
        w1v[0] = (f32x2){t1a.x, t1a.y}; w1v[1] = (f32x2){t1a.z, t1a.w};
        w1v[2] = (f32x2){t1b.x, t1b.y}; w1v[3] = (f32x2){t1b.z, t1b.w};
        bbv[0] = (f32x2){tba.x, tba.y}; bbv[1] = (f32x2){tba.z, tba.w};
        bbv[2] = (f32x2){tbb.x, tbb.y}; bbv[3] = (f32x2){tbb.z, tbb.w};
        #pragma unroll
        for (int ms = 0; ms < 4; ++ms) {
          const int row = ms * 16 + lm;
          const unsigned int xu = *(const unsigned int*)&obs_s[row * OBS_STRIDE + 2 * gp];
          const f32x2 x0v = {u2f(xu << 16), u2f(xu << 16)};
          const f32x2 x1v = {u2f(xu & 0xffff0000u), u2f(xu & 0xffff0000u)};
          unsigned int au[4];
          #pragma unroll
          for (int jj = 0; jj < 4; ++jj) {
            f32x2 h = bbv[jj] + x0v * w0v[jj] + x1v * w1v[jj];
            h = __builtin_elementwise_max(h, h * NEG_SLOPE);
            au[jj] = pk2bf(h.x, h.y);
          }
          __builtin_memcpy(&apf[ms], au, 16);
        }
      }

      // 2) W2 B-frags + scalar branch biases
      const int ebase = (p * 18 + kt) * 6;
      bf16x8 wpf[2], wef[2], wof[2];
      float bp[2], be[2], bo[2];
      #pragma unroll
      for (int nt2 = 0; nt2 < 2; ++nt2) {
        wpf[nt2] = *(const bf16x8*)&encB[(ebase + nt2) * 512 + l * 8];
        wef[nt2] = *(const bf16x8*)&encB[(ebase + 2 + nt2) * 512 + l * 8];
        wof[nt2] = *(const bf16x8*)&encB[(ebase + 4 + nt2) * 512 + l * 8];
        const int nc = nt2 * 16 + lm;
        bp[nt2] = propB2[(p * 9 + gp) * 64 + (kt & 1) * 32 + nc];
        be[nt2] = extB2[(p * 2 + ge) * 288 + (kt - ge * 9) * 32 + nc];
        bo[nt2] = oppB2[p * 576 + kt * 32 + nc];
      }

      // 3) MFMAs sequenced per nt2, packed epilogue
      #pragma unroll
      for (int ms = 0; ms < 4; ++ms) {
        const int row = ms * 16 + lm;
        bf16x8 ae = *(const bf16x8*)&Hs[row * HS_STRIDE + ge * 32 + q * 8];
        bf16x8 ao = *(const bf16x8*)&Hs[row * HS_STRIDE + 64 + q * 8];
        f32x4 s0, s1;
        {
          f32x4 cp = __builtin_amdgcn_mfma_f32_16x16x32_bf16(apf[ms], wpf[0], zz, 0, 0, 0);
          f32x4 ce = __builtin_amdgcn_mfma_f32_16x16x32_bf16(ae,      wef[0], zz, 0, 0, 0);
          f32x4 co = __builtin_amdgcn_mfma_f32_16x16x32_bf16(ao,      wof[0], zz, 0, 0, 0);
          s0 = lrelu4(cp + splat4(bp[0])) + lrelu4(ce + splat4(be[0])) + lrelu4(co + splat4(bo[0]));
        }
        {
          f32x4 cp = __builtin_amdgcn_mfma_f32_16x16x32_bf16(apf[ms], wpf[1], zz, 0, 0, 0);
          f32x4 ce = __builtin_amdgcn_mfma_f32_16x16x32_bf16(ae,      wef[1], zz, 0, 0, 0);
          f32x4 co = __builtin_amdgcn_mfma_f32_16x16x32_bf16(ao,      wof[1], zz, 0, 0, 0);
          s1 = lrelu4(cp + splat4(bp[1])) + lrelu4(ce + splat4(be[1])) + lrelu4(co + splat4(bo[1]));
        }
        #pragma unroll
        for (int r = 0; r < 4; ++r)
          *(unsigned int*)&hbuf[(ms * 16 + q * 4 + r) * ENC_STRIDE + ktloc * 32 + lm * 2] =
              pk2bf(s0[r], s1[r]);
      }
    }
    __syncthreads();

    // --- pi L1 partial over this group's 6 k-tiles (all 8 waves) ---
    for (int ktloc = 0; ktloc < 6; ++ktloc) {
      const int kt = g * 6 + ktloc;
      bf16x8 afr[4], bfr[2];
      #pragma unroll
      for (int ms = 0; ms < 4; ++ms)
        afr[ms] = *(const bf16x8*)&hbuf[(ms * 16 + lm) * ENC_STRIDE + ktloc * 32 + q * 8];
      const int wb = ((p * 18 + kt) * 16 + wv * 2) * 512 + l * 8;
      bfr[0] = *(const bf16x8*)&w1sw[wb];
      bfr[1] = *(const bf16x8*)&w1sw[wb + 512];
      #pragma unroll
      for (int ms = 0; ms < 4; ++ms) {
        acc[ms][0] = __builtin_amdgcn_mfma_f32_16x16x32_bf16(afr[ms], bfr[0], acc[ms][0], 0, 0, 0);
        acc[ms][1] = __builtin_amdgcn_mfma_f32_16x16x32_bf16(afr[ms], bfr[1], acc[ms][1], 0, 0, 0);
      }
    }
    __syncthreads();
  }

  // ---- h1 epilogue (packed lrelu, pair-packed store into wave's strip) ----
  #pragma unroll
  for (int ms = 0; ms < 4; ++ms) {
    f32x4 a0 = lrelu4(acc[ms][0]);
    f32x4 a1 = lrelu4(acc[ms][1]);
    #pragma unroll
    for (int r = 0; r < 4; ++r)
      *(unsigned int*)&hbuf[(ms * 16 + q * 4 + r) * H_STRIDE + wv * 32 + lm * 2] =
          pk2bf(a0[r], a1[r]);
  }
  __syncthreads();

  // ---- pi L2: 256 -> 256 (bias in C) ----
  {
    float b2r0 = b2v[p * 256 + wv * 32 + lm];
    float b2r1 = b2v[p * 256 + wv * 32 + 16 + lm];
    #pragma unroll
    for (int a = 0; a < 4; ++a) {
      acc[a][0] = splat4(b2r0);
      acc[a][1] = splat4(b2r1);
    }
  }
  for (int kt = 0; kt < 8; ++kt) {
    bf16x8 afr[4], bfr[2];
    #pragma unroll
    for (int ms = 0; ms < 4; ++ms)
      afr[ms] = *(const bf16x8*)&hbuf[(ms * 16 + lm) * H_STRIDE + kt * 32 + q * 8];
    const int wb = ((p * 8 + kt) * 16 + wv * 2) * 512 + l * 8;
    bfr[0] = *(const bf16x8*)&w2sw[wb];
    bfr[1] = *(const bf16x8*)&w2sw[wb + 512];
    #pragma unroll
    for (int ms = 0; ms < 4; ++ms) {
      acc[ms][0] = __builtin_amdgcn_mfma_f32_16x16x32_bf16(afr[ms], bfr[0], acc[ms][0], 0, 0, 0);
      acc[ms][1] = __builtin_amdgcn_mfma_f32_16x16x32_bf16(afr[ms], bfr[1], acc[ms][1], 0, 0, 0);
    }
  }
  __syncthreads();                 // all h1 reads complete before overwrite
  #pragma unroll
  for (int ms = 0; ms < 4; ++ms) {
    f32x4 a0 = lrelu4(acc[ms][0]);
    f32x4 a1 = lrelu4(acc[ms][1]);
    #pragma unroll
    for (int r = 0; r < 4; ++r)
      *(unsigned int*)&hbuf[(ms * 16 + q * 4 + r) * H_STRIDE + wv * 32 + lm * 2] =
          pk2bf(a0[r], a1[r]);
  }
  __syncthreads();

  // ---- pi L3: 256 -> 3 (N padded to 16) + tanh, waves 0..3 ----
  if (wv < 4) {
    const float bias3 = (lm < 3) ? b3v[p * 3 + lm] : 0.f;
    f32x4 a3 = splat4(bias3);
    for (int kt = 0; kt < 8; ++kt) {
      bf16x8 afr = *(const bf16x8*)&hbuf[(wv * 16 + lm) * H_STRIDE + kt * 32 + q * 8];
      bf16x8 bfr = *(const bf16x8*)&w3sw[((p * 8 + kt) * 64 + l) * 8];
      a3 = __builtin_amdgcn_mfma_f32_16x16x32_bf16(afr, bfr, a3, 0, 0, 0);
    }
    if (lm < 3) {
      #pragma unroll
      for (int r = 0; r < 4; ++r) {
        const int s = wv * 16 + q * 4 + r;
        out[(sbase + s) * 9 + p * 3 + lm] = tanhf(a3[r]);
      }
    }
  }
}

// ---------------------------------------------------------------------------
extern "C" void kernel_launch(void* const* d_in, const int* in_sizes, int n_in,
                              void* d_out, int out_size, void* d_ws, size_t ws_size,
                              hipStream_t stream)
{
  (void)in_sizes; (void)n_in; (void)out_size; (void)ws_size;
  const float* obs    = (const float*)d_in[0];
  const float* propW1 = (const float*)d_in[1];
  const float* propB1 = (const float*)d_in[2];
  const float* propW2 = (const float*)d_in[3];
  const float* propB2 = (const float*)d_in[4];
  const float* extW1  = (const float*)d_in[5];
  const float* extB1  = (const float*)d_in[6];
  const float* extW2  = (const float*)d_in[7];
  const float* extB2  = (const float*)d_in[8];
  const float* oppW1  = (const float*)d_in[9];
  const float* oppB1  = (const float*)d_in[10];
  const float* oppW2  = (const float*)d_in[11];
  const float* oppB2  = (const float*)d_in[12];
  const float* piW1   = (const float*)d_in[13];
  const float* piB1   = (const float*)d_in[14];
  const float* piW2   = (const float*)d_in[15];
  const float* piB2   = (const float*)d_in[16];
  const float* piW3   = (const float*)d_in[17];
  const float* piB3   = (const float*)d_in[18];
  float* out = (float*)d_out;
  unsigned short* ws16 = (unsigned short*)d_ws;

  prep_kernel<<<dim3(((WS_TOTAL >> 3) + 255) / 256), dim3(256), 0, stream>>>(
      propW2, extW1, extW2, oppW1, oppW2, piW1, piW2, piW3, ws16);

  fused_kernel<<<dim3(65536 / 64, 3), dim3(512), 0, stream>>>(
      obs, propW1, propB1, propB2, extB1, extB2, oppB1, oppB2,
      ws16, piB1, piB2, piB3, out);
}

// Round 8
// 259.499 us; speedup vs baseline: 1.6423x; 1.6423x over previous
//
#include <hip/hip_runtime.h>
#include <math.h>

// ---------------------------------------------------------------------------
// MLPAC_4_team fused v8: B=65536, P=3.
// v7 -> v8: same 512-thread / 8-wave structure, but __launch_bounds__(512,4)
// (VGPR cap 128, not 85). R7's (512,6) cap=85 forced a total spill
// (VGPR 40, 1.17 GB scratch traffic). 2 blocks/CU x 8 waves = 16 waves/CU.
// prep_kernel unchanged. ~80us of bench total is fixed harness reset cost.
// ---------------------------------------------------------------------------

#define NEG_SLOPE 0.01f

// ws offsets in ushort elements
#define OFF_B1A  0
#define OFF_ENCB 9216
#define OFF_PW1  175104
#define OFF_PW2  617472
#define OFF_PW3  814080
#define WS_TOTAL 826368

// tile (512-short) boundaries
#define TILE_ENCB 18
#define TILE_PW1  342
#define TILE_PW2  1206
#define TILE_PW3  1590

#define OBS_STRIDE 48     // shorts/row (96 B)
#define HS_STRIDE  104    // shorts/row (96 used: ext0|ext1|opp)
#define ENC_STRIDE 200    // shorts/row (6*32 used)
#define H_STRIDE   264    // shorts/row (256 used)

typedef short bf16x8 __attribute__((ext_vector_type(8)));
typedef float f32x4  __attribute__((ext_vector_type(4)));
typedef float f32x2  __attribute__((ext_vector_type(2)));

__device__ __forceinline__ float lrelu(float x) { return fmaxf(x, NEG_SLOPE * x); }

__device__ __forceinline__ f32x4 lrelu4(f32x4 x) {
  return __builtin_elementwise_max(x, x * NEG_SLOPE);
}
__device__ __forceinline__ f32x4 splat4(float b) { return (f32x4){b, b, b, b}; }

__device__ __forceinline__ float u2f(unsigned int u) {
  union { unsigned int u; float f; } c; c.u = u; return c.f;
}

// pack two f32 -> two bf16 (round-half-up) in one v_perm_b32
__device__ __forceinline__ unsigned int pk2bf(float a, float b) {
  union { float f; unsigned int u; } ca, cb; ca.f = a; cb.f = b;
  return __builtin_amdgcn_perm(cb.u + 0x8000u, ca.u + 0x8000u, 0x07060302u);
}

__device__ __forceinline__ unsigned short f2bf(float x) {  // RNE, prep only
  union { float f; unsigned int u; } c; c.f = x;
  unsigned int u = (c.u + 0x7fffu + ((c.u >> 16) & 1u)) >> 16;
  return (unsigned short)u;
}

// ---------------------------------------------------------------------------
// prep (v6): one thread = one frag row (lane) = 8 shorts = one uint4 store.
// B-frag layout: lane l holds B[k_pos=(l>>4)*8+j][n=l&15], j=0..7.
// kperm = (k_pos&1)*16 + (k_pos>>1) absorbs the pair-pack column permutation.
// ---------------------------------------------------------------------------
__global__ __launch_bounds__(256) void prep_kernel(
    const float* __restrict__ propW2, const float* __restrict__ extW1,
    const float* __restrict__ extW2,  const float* __restrict__ oppW1,
    const float* __restrict__ oppW2,  const float* __restrict__ piW1,
    const float* __restrict__ piW2,   const float* __restrict__ piW3,
    unsigned short* __restrict__ ws16)
{
  const int u = blockIdx.x * 256 + threadIdx.x;   // frag-row index
  if (u >= (WS_TOTAL >> 3)) return;
  const int lane = u & 63;
  const int t = u >> 6;                            // 512-short tile index
  const int lm = lane & 15;
  const int kbase = (lane >> 4) << 3;              // k_pos = kbase + j

  unsigned short o8[8];

  if (t < TILE_ENCB) {
    int s = t;
    const int nt2 = s & 1; s >>= 1;
    const int go = s % 3; const int p = s / 3;
    const int n = go * 32 + nt2 * 16 + lm;
    #pragma unroll
    for (int j = 0; j < 8; ++j) {
      const int d = 16 + kbase + j;
      float v;
      if (n < 64) {
        const int g = n >> 5, o = n & 31, i = d - 18 - 6 * g;
        v = (i >= 0 && i < 6) ? extW1[((p * 2 + g) * 6 + i) * 32 + o] : 0.f;
      } else {
        const int o = n - 64, i = d - 30;
        v = (i >= 0) ? oppW1[(p * 18 + i) * 32 + o] : 0.f;
      }
      o8[j] = f2bf(v);
    }
  } else if (t < TILE_PW1) {
    int s = t - TILE_ENCB;
    const int nt2 = s & 1; s >>= 1;
    const int br = s % 3; s /= 3;
    const int kt = s % 18; const int p = s / 18;
    const int n = kt * 32 + nt2 * 16 + lm;
    #pragma unroll
    for (int j = 0; j < 8; ++j) {
      const int k_pos = kbase + j;
      const int kperm = (k_pos & 1) * 16 + (k_pos >> 1);
      float v;
      if (br == 0)      { const int g = kt >> 1;   v = propW2[((p*9+g)*32 + k_pos)*64 + (n - g*64)]; }
      else if (br == 1) { const int g = (kt >= 9); v = extW2 [((p*2+g)*32 + kperm)*288 + (n - g*288)]; }
      else              {                          v = oppW2 [(p*32 + kperm)*576 + n]; }
      o8[j] = f2bf(v);
    }
  } else if (t < TILE_PW2) {
    int s = t - TILE_PW1;
    const int nt = s & 15; s >>= 4;
    const int kt = s % 18; const int p = s / 18;
    const int col = nt * 16 + lm;
    #pragma unroll
    for (int j = 0; j < 8; ++j) {
      const int k_pos = kbase + j;
      const int kperm = (k_pos & 1) * 16 + (k_pos >> 1);
      o8[j] = f2bf(piW1[(p * 576 + kt * 32 + kperm) * 256 + col]);
    }
  } else if (t < TILE_PW3) {
    int s = t - TILE_PW2;
    const int nt = s & 15; s >>= 4;
    const int kt = s & 7; const int p = s >> 3;
    const int col = nt * 16 + lm;
    #pragma unroll
    for (int j = 0; j < 8; ++j) {
      const int k_pos = kbase + j;
      const int kperm = (k_pos & 1) * 16 + (k_pos >> 1);
      o8[j] = f2bf(piW2[(p * 256 + kt * 32 + kperm) * 256 + col]);
    }
  } else {
    int s = t - TILE_PW3;
    const int kt = s & 7; const int p = s >> 3;
    #pragma unroll
    for (int j = 0; j < 8; ++j) {
      const int k_pos = kbase + j;
      const int kperm = (k_pos & 1) * 16 + (k_pos >> 1);
      o8[j] = (lm < 3) ? f2bf(piW3[(p * 256 + kt * 32 + kperm) * 3 + lm]) : (unsigned short)0;
    }
  }

  *(uint4*)&ws16[(size_t)u * 8] = *(const uint4*)o8;
}

// ---------------------------------------------------------------------------
__global__ __launch_bounds__(512, 4) void fused_kernel(
    const float* __restrict__ obs,
    const float* __restrict__ propW1, const float* __restrict__ propB1,
    const float* __restrict__ propB2,
    const float* __restrict__ extB1,  const float* __restrict__ extB2,
    const float* __restrict__ oppB1,  const float* __restrict__ oppB2,
    const unsigned short* __restrict__ wsAll,
    const float* __restrict__ b1v, const float* __restrict__ b2v,
    const float* __restrict__ b3v,
    float* __restrict__ out)
{
  __shared__ __align__(16) unsigned short obs_s[64 * OBS_STRIDE]; //  6144 B
  __shared__ __align__(16) unsigned short Hs[64 * HS_STRIDE];     // 13312 B
  __shared__ __align__(16) unsigned short hbuf[64 * H_STRIDE];    // 33792 B
  // total 53248 B -> 2 blocks/CU (512 thr), 16 waves/CU, VGPR cap 128

  const unsigned short* b1aW = wsAll + OFF_B1A;
  const unsigned short* encB = wsAll + OFF_ENCB;
  const unsigned short* w1sw = wsAll + OFF_PW1;
  const unsigned short* w2sw = wsAll + OFF_PW2;
  const unsigned short* w3sw = wsAll + OFF_PW3;

  const int tid = threadIdx.x;
  const int p = blockIdx.y, brow = blockIdx.x;
  const int sbase = brow * 64;
  const int wv = tid >> 6, l = tid & 63, lm = l & 15, q = l >> 4;
  const f32x4 zz = {0.f, 0.f, 0.f, 0.f};

  // ---- phase 0: obs -> LDS bf16 (first 4 waves) ----
  if (tid < 256) {
    const int s = tid >> 2, c4 = tid & 3;
    if (c4 < 3) {
      const int c0 = c4 * 16;
      const float4* src = (const float4*)&obs[(sbase + s) * 144 + p * 48 + c0];
      float4 v0 = src[0], v1 = src[1], v2 = src[2], v3 = src[3];
      unsigned int pk[8];
      pk[0] = pk2bf(v0.x, v0.y); pk[1] = pk2bf(v0.z, v0.w);
      pk[2] = pk2bf(v1.x, v1.y); pk[3] = pk2bf(v1.z, v1.w);
      pk[4] = pk2bf(v2.x, v2.y); pk[5] = pk2bf(v2.z, v2.w);
      pk[6] = pk2bf(v3.x, v3.y); pk[7] = pk2bf(v3.z, v3.w);
      *(uint4*)&obs_s[s * OBS_STRIDE + c0]     = *(uint4*)&pk[0];
      *(uint4*)&obs_s[s * OBS_STRIDE + c0 + 8] = *(uint4*)&pk[4];
    }
  }
  __syncthreads();

  // ---- phase 1a: ext+opp layer-1 via MFMA (waves 1..3), bias in C ----
  if (wv >= 1 && wv <= 3) {
    const int go = wv - 1;                      // 0: ext0, 1: ext1, 2: opp
    bf16x8 af[4];
    #pragma unroll
    for (int ms = 0; ms < 4; ++ms)
      af[ms] = *(const bf16x8*)&obs_s[(ms * 16 + lm) * OBS_STRIDE + 16 + q * 8];
    bf16x8 bf0 = *(const bf16x8*)&b1aW[((p * 3 + go) * 2 + 0) * 512 + l * 8];
    bf16x8 bf1 = *(const bf16x8*)&b1aW[((p * 3 + go) * 2 + 1) * 512 + l * 8];
    float bias0, bias1;
    if (go < 2) { bias0 = extB1[(p*2+go)*32 + lm]; bias1 = extB1[(p*2+go)*32 + 16 + lm]; }
    else        { bias0 = oppB1[p*32 + lm];        bias1 = oppB1[p*32 + 16 + lm]; }
    const f32x4 cb0 = splat4(bias0), cb1 = splat4(bias1);
    #pragma unroll
    for (int ms = 0; ms < 4; ++ms) {
      f32x4 c0 = lrelu4(__builtin_amdgcn_mfma_f32_16x16x32_bf16(af[ms], bf0, cb0, 0, 0, 0));
      f32x4 c1 = lrelu4(__builtin_amdgcn_mfma_f32_16x16x32_bf16(af[ms], bf1, cb1, 0, 0, 0));
      #pragma unroll
      for (int r = 0; r < 4; ++r)
        *(unsigned int*)&Hs[(ms * 16 + q * 4 + r) * HS_STRIDE + go * 32 + lm * 2] =
            pk2bf(c0[r], c1[r]);
    }
  }
  __syncthreads();

  // ---- pi L1 bias preload + acc init (wave owns 32-col strip wv*32..) ----
  float b1r[2];
  #pragma unroll
  for (int nt = 0; nt < 2; ++nt) b1r[nt] = b1v[p * 256 + wv * 32 + nt * 16 + lm];
  f32x4 acc[4][2];
  #pragma unroll
  for (int a = 0; a < 4; ++a) {
    acc[a][0] = splat4(b1r[0]);
    acc[a][1] = splat4(b1r[1]);
  }

  // ---- enc: 3 groups x 6 kt (1 kt per wave, waves 0..5) + pi-L1 partial ----
  for (int g = 0; g < 3; ++g) {
    if (wv < 6) {
      const int kt = g * 6 + wv, ktloc = wv;
      const int gp = kt >> 1, ge = (kt >= 9) ? 1 : 0;

      // 1) prop-H A-frags first (prop weights die before W2 frags)
      bf16x8 apf[4];
      {
        f32x2 w0v[4], w1v[4], bbv[4];
        const float4* p4 = (const float4*)&propW1[(p * 9 + gp) * 64];
        float4 t0a = p4[q * 2],     t0b = p4[q * 2 + 1];
        float4 t1a = p4[8 + q * 2], t1b = p4[8 + q * 2 + 1];
        const float4* pb4 = (const float4*)&propB1[(p * 9 + gp) * 32];
        float4 tba = pb4[q * 2],    tbb = pb4[q * 2 + 1];
        w0v[0] = (f32x2){t0a.x, t0a.y}; w0v[1] = (f32x2){t0a.z, t0a.w};
        w0v[2] = (f32x2){t0b.x, t0b.y}; w0v[3] = (f32x2){t0b.z, t0b.w};
        w1v[0] = (f32x2){t1a.x, t1a.y}; w1v[1] = (f32x2){t1a.z, t1a.w};
        w1v[2] = (f32x2){t1b.x, t1b.y}; w1v[3] = (f32x2){t1b.z, t1b.w};
        bbv[0] = (f32x2){tba.x, tba.y}; bbv[1] = (f32x2){tba.z, tba.w};
        bbv[2] = (f32x2){tbb.x, tbb.y}; bbv[3] = (f32x2){tbb.z, tbb.w};
        #pragma unroll
        for (int ms = 0; ms < 4; ++ms) {
          const int row = ms * 16 + lm;
          const unsigned int xu = *(const unsigned int*)&obs_s[row * OBS_STRIDE + 2 * gp];
          const f32x2 x0v = {u2f(xu << 16), u2f(xu << 16)};
          const f32x2 x1v = {u2f(xu & 0xffff0000u), u2f(xu & 0xffff0000u)};
          unsigned int au[4];
          #pragma unroll
          for (int jj = 0; jj < 4; ++jj) {
            f32x2 h = bbv[jj] + x0v * w0v[jj] + x1v * w1v[jj];
            h = __builtin_elementwise_max(h, h * NEG_SLOPE);
            au[jj] = pk2bf(h.x, h.y);
          }
          __builtin_memcpy(&apf[ms], au, 16);
        }
      }

      // 2) W2 B-frags + scalar branch biases
      const int ebase = (p * 18 + kt) * 6;
      bf16x8 wpf[2], wef[2], wof[2];
      float bp[2], be[2], bo[2];
      #pragma unroll
      for (int nt2 = 0; nt2 < 2; ++nt2) {
        wpf[nt2] = *(const bf16x8*)&encB[(ebase + nt2) * 512 + l * 8];
        wef[nt2] = *(const bf16x8*)&encB[(ebase + 2 + nt2) * 512 + l * 8];
        wof[nt2] = *(const bf16x8*)&encB[(ebase + 4 + nt2) * 512 + l * 8];
        const int nc = nt2 * 16 + lm;
        bp[nt2] = propB2[(p * 9 + gp) * 64 + (kt & 1) * 32 + nc];
        be[nt2] = extB2[(p * 2 + ge) * 288 + (kt - ge * 9) * 32 + nc];
        bo[nt2] = oppB2[p * 576 + kt * 32 + nc];
      }

      // 3) MFMAs sequenced per nt2, packed epilogue
      #pragma unroll
      for (int ms = 0; ms < 4; ++ms) {
        const int row = ms * 16 + lm;
        bf16x8 ae = *(const bf16x8*)&Hs[row * HS_STRIDE + ge * 32 + q * 8];
        bf16x8 ao = *(const bf16x8*)&Hs[row * HS_STRIDE + 64 + q * 8];
        f32x4 s0, s1;
        {
          f32x4 cp = __builtin_amdgcn_mfma_f32_16x16x32_bf16(apf[ms], wpf[0], zz, 0, 0, 0);
          f32x4 ce = __builtin_amdgcn_mfma_f32_16x16x32_bf16(ae,      wef[0], zz, 0, 0, 0);
          f32x4 co = __builtin_amdgcn_mfma_f32_16x16x32_bf16(ao,      wof[0], zz, 0, 0, 0);
          s0 = lrelu4(cp + splat4(bp[0])) + lrelu4(ce + splat4(be[0])) + lrelu4(co + splat4(bo[0]));
        }
        {
          f32x4 cp = __builtin_amdgcn_mfma_f32_16x16x32_bf16(apf[ms], wpf[1], zz, 0, 0, 0);
          f32x4 ce = __builtin_amdgcn_mfma_f32_16x16x32_bf16(ae,      wef[1], zz, 0, 0, 0);
          f32x4 co = __builtin_amdgcn_mfma_f32_16x16x32_bf16(ao,      wof[1], zz, 0, 0, 0);
          s1 = lrelu4(cp + splat4(bp[1])) + lrelu4(ce + splat4(be[1])) + lrelu4(co + splat4(bo[1]));
        }
        #pragma unroll
        for (int r = 0; r < 4; ++r)
          *(unsigned int*)&hbuf[(ms * 16 + q * 4 + r) * ENC_STRIDE + ktloc * 32 + lm * 2] =
              pk2bf(s0[r], s1[r]);
      }
    }
    __syncthreads();

    // --- pi L1 partial over this group's 6 k-tiles (all 8 waves) ---
    for (int ktloc = 0; ktloc < 6; ++ktloc) {
      const int kt = g * 6 + ktloc;
      bf16x8 afr[4], bfr[2];
      #pragma unroll
      for (int ms = 0; ms < 4; ++ms)
        afr[ms] = *(const bf16x8*)&hbuf[(ms * 16 + lm) * ENC_STRIDE + ktloc * 32 + q * 8];
      const int wb = ((p * 18 + kt) * 16 + wv * 2) * 512 + l * 8;
      bfr[0] = *(const bf16x8*)&w1sw[wb];
      bfr[1] = *(const bf16x8*)&w1sw[wb + 512];
      #pragma unroll
      for (int ms = 0; ms < 4; ++ms) {
        acc[ms][0] = __builtin_amdgcn_mfma_f32_16x16x32_bf16(afr[ms], bfr[0], acc[ms][0], 0, 0, 0);
        acc[ms][1] = __builtin_amdgcn_mfma_f32_16x16x32_bf16(afr[ms], bfr[1], acc[ms][1], 0, 0, 0);
      }
    }
    __syncthreads();
  }

  // ---- h1 epilogue (packed lrelu, pair-packed store into wave's strip) ----
  #pragma unroll
  for (int ms = 0; ms < 4; ++ms) {
    f32x4 a0 = lrelu4(acc[ms][0]);
    f32x4 a1 = lrelu4(acc[ms][1]);
    #pragma unroll
    for (int r = 0; r < 4; ++r)
      *(unsigned int*)&hbuf[(ms * 16 + q * 4 + r) * H_STRIDE + wv * 32 + lm * 2] =
          pk2bf(a0[r], a1[r]);
  }
  __syncthreads();

  // ---- pi L2: 256 -> 256 (bias in C) ----
  {
    float b2r0 = b2v[p * 256 + wv * 32 + lm];
    float b2r1 = b2v[p * 256 + wv * 32 + 16 + lm];
    #pragma unroll
    for (int a = 0; a < 4; ++a) {
      acc[a][0] = splat4(b2r0);
      acc[a][1] = splat4(b2r1);
    }
  }
  for (int kt = 0; kt < 8; ++kt) {
    bf16x8 afr[4], bfr[2];
    #pragma unroll
    for (int ms = 0; ms < 4; ++ms)
      afr[ms] = *(const bf16x8*)&hbuf[(ms * 16 + lm) * H_STRIDE + kt * 32 + q * 8];
    const int wb = ((p * 8 + kt) * 16 + wv * 2) * 512 + l * 8;
    bfr[0] = *(const bf16x8*)&w2sw[wb];
    bfr[1] = *(const bf16x8*)&w2sw[wb + 512];
    #pragma unroll
    for (int ms = 0; ms < 4; ++ms) {
      acc[ms][0] = __builtin_amdgcn_mfma_f32_16x16x32_bf16(afr[ms], bfr[0], acc[ms][0], 0, 0, 0);
      acc[ms][1] = __builtin_amdgcn_mfma_f32_16x16x32_bf16(afr[ms], bfr[1], acc[ms][1], 0, 0, 0);
    }
  }
  __syncthreads();                 // all h1 reads complete before overwrite
  #pragma unroll
  for (int ms = 0; ms < 4; ++ms) {
    f32x4 a0 = lrelu4(acc[ms][0]);
    f32x4 a1 = lrelu4(acc[ms][1]);
    #pragma unroll
    for (int r = 0; r < 4; ++r)
      *(unsigned int*)&hbuf[(ms * 16 + q * 4 + r) * H_STRIDE + wv * 32 + lm * 2] =
          pk2bf(a0[r], a1[r]);
  }
  __syncthreads();

  // ---- pi L3: 256 -> 3 (N padded to 16) + tanh, waves 0..3 ----
  if (wv < 4) {
    const float bias3 = (lm < 3) ? b3v[p * 3 + lm] : 0.f;
    f32x4 a3 = splat4(bias3);
    for (int kt = 0; kt < 8; ++kt) {
      bf16x8 afr = *(const bf16x8*)&hbuf[(wv * 16 + lm) * H_STRIDE + kt * 32 + q * 8];
      bf16x8 bfr = *(const bf16x8*)&w3sw[((p * 8 + kt) * 64 + l) * 8];
      a3 = __builtin_amdgcn_mfma_f32_16x16x32_bf16(afr, bfr, a3, 0, 0, 0);
    }
    if (lm < 3) {
      #pragma unroll
      for (int r = 0; r < 4; ++r) {
        const int s = wv * 16 + q * 4 + r;
        out[(sbase + s) * 9 + p * 3 + lm] = tanhf(a3[r]);
      }
    }
  }
}

// ---------------------------------------------------------------------------
extern "C" void kernel_launch(void* const* d_in, const int* in_sizes, int n_in,
                              void* d_out, int out_size, void* d_ws, size_t ws_size,
                              hipStream_t stream)
{
  (void)in_sizes; (void)n_in; (void)out_size; (void)ws_size;
  const float* obs    = (const float*)d_in[0];
  const float* propW1 = (const float*)d_in[1];
  const float* propB1 = (const float*)d_in[2];
  const float* propW2 = (const float*)d_in[3];
  const float* propB2 = (const float*)d_in[4];
  const float* extW1  = (const float*)d_in[5];
  const float* extB1  = (const float*)d_in[6];
  const float* extW2  = (const float*)d_in[7];
  const float* extB2  = (const float*)d_in[8];
  const float* oppW1  = (const float*)d_in[9];
  const float* oppB1  = (const float*)d_in[10];
  const float* oppW2  = (const float*)d_in[11];
  const float* oppB2  = (const float*)d_in[12];
  const float* piW1   = (const float*)d_in[13];
  const float* piB1   = (const float*)d_in[14];
  const float* piW2   = (const float*)d_in[15];
  const float* piB2   = (const float*)d_in[16];
  const float* piW3   = (const float*)d_in[17];
  const float* piB3   = (const float*)d_in[18];
  float* out = (float*)d_out;
  unsigned short* ws16 = (unsigned short*)d_ws;

  prep_kernel<<<dim3(((WS_TOTAL >> 3) + 255) / 256), dim3(256), 0, stream>>>(
      propW2, extW1, extW2, oppW1, oppW2, piW1, piW2, piW3, ws16);

  fused_kernel<<<dim3(65536 / 64, 3), dim3(512), 0, stream>>>(
      obs, propW1, propB1, propB2, extB1, extB2, oppB1, oppB2,
      ws16, piB1, piB2, piB3, out);
}